// Round 18
// baseline (177.000 us; speedup 1.0000x reference)
//
#include <hip/hip_runtime.h>

// ---- problem constants (from reference) ----
#define SEQ      10688      // IMG_LEN + TEXT_LEN
#define IMG_LEN  10368      // 18*24*24
#define TEXT_LEN 320
#define DH       128
#define NHEADS   4
#define SLAB     3456       // 6*24*24 tokens per time-slab
#define KVC      32         // kv chunk rows
#define QT       128        // q rows per merge tile (4 x 32-row wave slices)
#define NIT      81         // image q-tiles per head
#define NTT      3          // text q-tiles per head (last tile half-valid)
#define NCH_TXT  334
#define NCH_IMG  118        // 108 slab chunks + 10 text chunks
#define SCALEL2E 0.12751744518924593f   // (1/sqrt(128)) * log2(e)
#define DEFER_THR 8.0f      // defer-max rescale threshold (T13)

typedef __bf16 bf16x8 __attribute__((ext_vector_type(8)));
typedef __bf16 bf16x4 __attribute__((ext_vector_type(4)));
typedef float  f32x4  __attribute__((ext_vector_type(4)));

__device__ __forceinline__ unsigned pk2bf(float a, float b) {
    union { __bf16 h[2]; unsigned u; } t;
    t.h[0] = (__bf16)a; t.h[1] = (__bf16)b;
    return t.u;
}

__device__ __forceinline__ bf16x8 as_bf16x8(uint4 u) {
    union { uint4 a; bf16x8 v; } t; t.a = u; return t.v;
}

__device__ __forceinline__ void split_range(int total, int nsplit, int s, int& c0, int& n) {
    const int q = total / nsplit, r = total % nsplit;
    if (s < r) { c0 = s * (q + 1); n = q + 1; }
    else       { c0 = r * (q + 1) + (s - r) * q; n = q; }
}

template<int TS, int IS> struct Geo {
    static constexpr int NTXTB = NHEADS * NTT * TS;
    static constexpr int NIMGB = NHEADS * NIT * IS;
    static constexpr int NPID  = NTXTB + NIMGB;
    static constexpr size_t WS_FLOATS = (size_t)NPID * (QT * DH + QT * 2);
};
#define KB_BYTES ((size_t)NHEADS * SEQ * DH * 2)   // bf16 K-frag (or V-frag) array

// ---- pre-pass: BOTH K and V to MFMA-fragment order (see R16/R17) ----
__global__ __launch_bounds__(256) void sta_prep(const float* __restrict__ Kg,
                                                const float* __restrict__ Vg,
                                                uint4* __restrict__ Kf,
                                                uint4* __restrict__ Vf) {
    __shared__ float T[64][65];
    const int b = blockIdx.x;
    if (b < NHEADS * 334) {              // K-frag: one block per (head, chunk)
        const int hb = b / 334, chunk = b % 334;
        const float* src = Kg + ((size_t)hb * SEQ + chunk * 32) * DH;
        const int t = threadIdx.x;
        #pragma unroll
        for (int i = 0; i < 2; ++i) {
            const int oidx = t + 256 * i;          // 0..511
            const int frag = oidx >> 6, lane = oidx & 63;
            const int c = frag >> 1, kt = frag & 1;
            const int row = kt * 16 + (lane & 15);
            const int col = c * 32 + (lane >> 4) * 8;
            float4 a = *(const float4*)(src + (size_t)row * DH + col);
            float4 d = *(const float4*)(src + (size_t)row * DH + col + 4);
            uint4 u; u.x = pk2bf(a.x, a.y); u.y = pk2bf(a.z, a.w);
                     u.z = pk2bf(d.x, d.y); u.w = pk2bf(d.z, d.w);
            Kf[((size_t)(hb * 334 + chunk) * 8 + frag) * 64 + lane] = u;
        }
    } else {                             // V: 64kv x 64d tile -> fragment order
        const int bb = b - NHEADS * 334;
        const int dhalf = bb & 1, kvt = (bb >> 1) % 167, h = (bb >> 1) / 167;
        const float* src = Vg + ((size_t)h * SEQ + kvt * 64) * DH + dhalf * 64;
        const int t = threadIdx.x;
        const int col = t & 63, r4 = t >> 6;
        #pragma unroll
        for (int i = 0; i < 16; ++i) {
            const int row = i * 4 + r4;
            T[row][col] = src[(size_t)row * DH + col];
        }
        __syncthreads();
        const int lane = t & 63, q = t & 15, gg = lane >> 4;
        #pragma unroll
        for (int i = 0; i < 2; ++i) {
            const int idx = (t >> 6) * 2 + i;      // 0..7: ch2(2) x kt(2) x dtp(2)
            const int ch2 = idx >> 2, kt = (idx >> 1) & 1, dtp = idx & 1;
            const int kvl = ch2 * 32 + kt * 16 + gg * 4;
            const int dle = dtp * 32 + q;          // d-local of even dt
            const int dlo = dle + 16;
            uint4 u;
            u.x = pk2bf(T[kvl][dle],     T[kvl + 1][dle]);
            u.y = pk2bf(T[kvl + 2][dle], T[kvl + 3][dle]);
            u.z = pk2bf(T[kvl][dlo],     T[kvl + 1][dlo]);
            u.w = pk2bf(T[kvl + 2][dlo], T[kvl + 3][dlo]);
            const size_t o4 = ((size_t)(h * 334 + kvt * 2 + ch2) * 8
                               + kt * 4 + dhalf * 2 + dtp) * 64 + lane;
            Vf[o4] = u;
        }
    }
}

// ONE-WAVE BLOCKS (64 threads): R17's waves were already fully independent
// (no LDS, no barriers) -- the 4-wave block only coarsened scheduling
// (5.4 blocks/CU demand vs 4-block cap -> 19% occupancy tail). Grid x4 at
// 64 threads: 21.8 blocks/CU demand, fine-grained packing. Compute body is
// byte-identical; wv moves from threadIdx to blockIdx. K/V frag L1-sharing
// becomes L2-sharing (~8 TB/s demand vs 34.5 ceiling -- safe).
// NOTE: NO min-waves clamp (rounds 3/5 spill catastrophe).
template<int TS, int IS, bool SPLIT>
__global__ __launch_bounds__(64) void sta_attn(const float* __restrict__ Qg,
                                               const uint4* __restrict__ Kf,
                                               const uint4* __restrict__ Vf,
                                               float* __restrict__ Og,
                                               float* __restrict__ Opart,
                                               float* __restrict__ Ml) {
    using G = Geo<TS, IS>;
    const int lane = threadIdx.x & 63;
    const int wv   = blockIdx.x & 3;          // 32-row slice of the 128-row tile
    const int q    = lane & 15;               // MFMA col position in S^T (q-tilde)
    const int g    = lane >> 4;               // lane group 0..3

    int b = blockIdx.x >> 2;
    int head, qbase, nch, ch0, kvb0, pid = 0;
    bool isText;
    if (b < G::NTXTB) {                        // text splits first (longest poles)
        int tb = b / TS, s = b % TS;
        head = tb / NTT; qbase = IMG_LEN + (tb % NTT) * QT;
        isText = true; kvb0 = 0;
        split_range(NCH_TXT, TS, s, ch0, nch);
        pid = b;
    } else {
        int bb = b - G::NTXTB; int tile = bb / IS, s = bb % IS;
        head = tile / NIT; qbase = (tile % NIT) * QT;
        isText = false; kvb0 = (qbase / SLAB) * SLAB;
        split_range(NCH_IMG, IS, s, ch0, nch);
        pid = G::NTXTB + bb;
    }

    const size_t hoff = (size_t)head * SEQ * DH;
    const float* Qh = Qg + hoff;
    const uint4* kfh = Kf + (size_t)head * 334 * 512 + lane;  // 512 uint4/chunk
    const uint4* vfh = Vf + (size_t)head * 334 * 512 + lane;

    // ---- Q fragments for 2 q-subtiles (B-operand layout), scale folded ----
    bf16x8 qf[2][4];
    #pragma unroll
    for (int n = 0; n < 2; ++n) {
        int qr = qbase + wv * 32 + n * 16 + q;
        if (qr > SEQ - 1) qr = SEQ - 1;        // text tail: clamp (discarded at store)
        const float* qp = Qh + (size_t)qr * DH;
        #pragma unroll
        for (int c = 0; c < 4; ++c) {
            float4 a = *(const float4*)(qp + c * 32 + g * 8);
            float4 d = *(const float4*)(qp + c * 32 + g * 8 + 4);
            union { unsigned u[4]; bf16x8 v; } t;
            t.u[0] = pk2bf(a.x * SCALEL2E, a.y * SCALEL2E);
            t.u[1] = pk2bf(a.z * SCALEL2E, a.w * SCALEL2E);
            t.u[2] = pk2bf(d.x * SCALEL2E, d.y * SCALEL2E);
            t.u[3] = pk2bf(d.z * SCALEL2E, d.w * SCALEL2E);
            qf[n][c] = t.v;
        }
    }

    // o layout (un-swapped PV): o[n][dt][r] = O[q = n*16+g*4+r][d = dt*16+qtilde]
    f32x4 o[2][8];
    #pragma unroll
    for (int n = 0; n < 2; ++n)
        #pragma unroll
        for (int dt = 0; dt < 8; ++dt) o[n][dt] = f32x4{0.f, 0.f, 0.f, 0.f};
    float mrun[2] = {-INFINITY, -INFINITY};    // stats in qtilde-space (lane&15)
    float lsum[2] = {0.f, 0.f};                // per-lane partial (deferred reduce)

    auto kvaddr = [&](int gch) -> int {
        return isText ? gch * KVC
                      : (gch < 108 ? kvb0 + gch * KVC : IMG_LEN + (gch - 108) * KVC);
    };

    // prologue: K fragments for chunk 0
    uint4 kf4[8];
    {
        const uint4* kp = kfh + (size_t)(kvaddr(ch0) >> 5) * 512;
        #pragma unroll
        for (int f = 0; f < 8; ++f) kf4[f] = kp[f * 64];
    }

    for (int ch = 0; ch < nch; ++ch) {
        const int kb = kvaddr(ch0 + ch);

        // ---- V fragments for THIS chunk (oldest in vmcnt queue; consumed at PV) ----
        const uint4* vp = vfh + (size_t)(kb >> 5) * 512;
        uint4 vf4[8];
        #pragma unroll
        for (int f = 0; f < 8; ++f) vf4[f] = vp[f * 64];

        // ---- S^T = K * Q^T from kf4 regs (prefetched last iteration) ----
        f32x4 st[2][2];
        #pragma unroll
        for (int n = 0; n < 2; ++n)
            #pragma unroll
            for (int kt = 0; kt < 2; ++kt) st[n][kt] = f32x4{0.f, 0.f, 0.f, 0.f};
        __builtin_amdgcn_s_setprio(1);
        #pragma unroll
        for (int c = 0; c < 4; ++c) {
            #pragma unroll
            for (int kt = 0; kt < 2; ++kt) {
                bf16x8 kf = as_bf16x8(kf4[c * 2 + kt]);
                st[0][kt] = __builtin_amdgcn_mfma_f32_16x16x32_bf16(kf, qf[0][c], st[0][kt], 0, 0, 0);
                st[1][kt] = __builtin_amdgcn_mfma_f32_16x16x32_bf16(kf, qf[1][c], st[1][kt], 0, 0, 0);
            }
        }
        __builtin_amdgcn_s_setprio(0);

        // ---- online softmax (log2 domain), defer-max ----
        float cm[2];
        #pragma unroll
        for (int n = 0; n < 2; ++n) {
            float a0 = fmaxf(fmaxf(st[n][0][0], st[n][0][1]), fmaxf(st[n][0][2], st[n][0][3]));
            float a1 = fmaxf(fmaxf(st[n][1][0], st[n][1][1]), fmaxf(st[n][1][2], st[n][1][3]));
            float c0 = fmaxf(a0, a1);
            c0 = fmaxf(c0, __shfl_xor(c0, 16));
            c0 = fmaxf(c0, __shfl_xor(c0, 32));
            cm[n] = c0;
        }
        if (!__all((cm[0] <= mrun[0] + DEFER_THR) && (cm[1] <= mrun[1] + DEFER_THR))) {
            #pragma unroll
            for (int n = 0; n < 2; ++n) {
                float mnew = fmaxf(mrun[n], cm[n]);
                float sc = exp2f(mrun[n] - mnew);
                lsum[n] *= sc;                 // per-lane partial: same sc, rows match
                mrun[n] = mnew;
                f32x4 scv;
                #pragma unroll
                for (int r = 0; r < 4; ++r)
                    scv[r] = __shfl(sc, (lane & 48) + g * 4 + r);
                #pragma unroll
                for (int dt = 0; dt < 8; ++dt) o[n][dt] *= scv;
            }
        }

        // P in bf16: A-operand layout (m=qtilde, k=g*4+r) IS the st layout.
        bf16x4 pkv[2][2];
        #pragma unroll
        for (int n = 0; n < 2; ++n) {
            float ps = 0.f;
            #pragma unroll
            for (int kt = 0; kt < 2; ++kt) {
                float p0 = exp2f(st[n][kt][0] - mrun[n]);
                float p1 = exp2f(st[n][kt][1] - mrun[n]);
                float p2 = exp2f(st[n][kt][2] - mrun[n]);
                float p3 = exp2f(st[n][kt][3] - mrun[n]);
                ps += (p0 + p1) + (p2 + p3);
                union { unsigned u[2]; bf16x4 v; } t;
                t.u[0] = pk2bf(p0, p1);
                t.u[1] = pk2bf(p2, p3);
                pkv[n][kt] = t.v;
            }
            lsum[n] += ps;
        }

        // ---- prefetch K(ch+1) into the now-dead kf4 regs (flies under PV) ----
        if (ch + 1 < nch) {
            const uint4* kp = kfh + (size_t)(kvaddr(ch0 + ch + 1) >> 5) * 512;
            #pragma unroll
            for (int f = 0; f < 8; ++f) kf4[f] = kp[f * 64];
        }

        // ---- O += P * V : A=pkv regs, B=V frags (registers), no LDS ----
        __builtin_amdgcn_s_setprio(1);
        #pragma unroll
        for (int kt = 0; kt < 2; ++kt) {
            #pragma unroll
            for (int dt = 0; dt < 8; ++dt) {
                bf16x4 vb = ((const bf16x4*)&vf4[kt * 4 + (dt >> 1)])[dt & 1];
                asm("v_mfma_f32_16x16x16_bf16 %0, %1, %2, %0"
                    : "+v"(o[0][dt]) : "v"(pkv[0][kt]), "v"(vb));
                asm("v_mfma_f32_16x16x16_bf16 %0, %1, %2, %0"
                    : "+v"(o[1][dt]) : "v"(pkv[1][kt]), "v"(vb));
            }
        }
        __builtin_amdgcn_s_setprio(0);
    }

    // hazard insurance: asm MFMA writes o[], epilogue VALU reads it soon after
    asm volatile("s_nop 7\n\ts_nop 7");

    // deferred lsum reduction: butterfly across the 4 groups (same qtilde row)
    #pragma unroll
    for (int n = 0; n < 2; ++n) {
        lsum[n] += __shfl_xor(lsum[n], 16);
        lsum[n] += __shfl_xor(lsum[n], 32);
    }

    if constexpr (SPLIT) {
        float* opb = Opart + (size_t)pid * (QT * DH);
        #pragma unroll
        for (int n = 0; n < 2; ++n) {
            #pragma unroll
            for (int r = 0; r < 4; ++r) {
                const int row = wv * 32 + n * 16 + g * 4 + r;
                float* op = opb + row * DH + q;
                #pragma unroll
                for (int dt = 0; dt < 8; ++dt) op[dt * 16] = o[n][dt][r];
            }
            if (g == 0) {
                const int srow = wv * 32 + n * 16 + q;
                Ml[(size_t)pid * (QT * 2) + srow * 2]     = mrun[n];
                Ml[(size_t)pid * (QT * 2) + srow * 2 + 1] = lsum[n];
            }
        }
    } else {
        #pragma unroll
        for (int n = 0; n < 2; ++n) {
            const float inv = 1.f / (lsum[n] + 64.f * exp2f(-mrun[n]));
            f32x4 invv;
            #pragma unroll
            for (int r = 0; r < 4; ++r)
                invv[r] = __shfl(inv, (lane & 48) + g * 4 + r);
            #pragma unroll
            for (int r = 0; r < 4; ++r) {
                const int qrow = qbase + wv * 32 + n * 16 + g * 4 + r;
                if (qrow >= SEQ) continue;
                float* op = Og + hoff + (size_t)qrow * DH + q;
                #pragma unroll
                for (int dt = 0; dt < 8; ++dt) op[dt * 16] = o[n][dt][r] * invv[r];
            }
        }
    }
}

// compile-time-S merge body (runtime-indexed local arrays would go to scratch)
template<int S>
__device__ __forceinline__ void merge_body(const float* __restrict__ Opart,
                                           const float* __restrict__ Ml,
                                           float* __restrict__ Og,
                                           int head, int qbase, int pbase,
                                           int row, int c4) {
    if (qbase + row >= SEQ) return;       // text tail
    float w[S], lv[S];
    float m = -INFINITY;
    #pragma unroll
    for (int s = 0; s < S; ++s) {
        w[s]  = Ml[(size_t)(pbase + s) * (QT * 2) + row * 2];
        lv[s] = Ml[(size_t)(pbase + s) * (QT * 2) + row * 2 + 1];
        m = fmaxf(m, w[s]);
    }
    float L = 64.f * exp2f(-m);           // 64 zero-pad keys (log2 domain)
    #pragma unroll
    for (int s = 0; s < S; ++s) { w[s] = exp2f(w[s] - m); L += w[s] * lv[s]; }
    const float inv = 1.f / L;

    float* op = Og + (size_t)head * SEQ * DH + (size_t)(qbase + row) * DH;
    #pragma unroll
    for (int half = 0; half < 2; ++half) {
        const int j = c4 + half * 16;
        float4 acc = make_float4(0.f, 0.f, 0.f, 0.f);
        #pragma unroll
        for (int s = 0; s < S; ++s) {
            const float4 p = *(const float4*)(Opart + (size_t)(pbase + s) * (QT * DH)
                                              + row * DH + j * 4);
            acc.x += w[s] * p.x; acc.y += w[s] * p.y;
            acc.z += w[s] * p.z; acc.w += w[s] * p.w;
        }
        float4 v; v.x = acc.x * inv; v.y = acc.y * inv; v.z = acc.z * inv; v.w = acc.w * inv;
        *(float4*)(op + j * 4) = v;
    }
}

// 8 blocks per q-tile (16-row slices): 2688 blocks -> not latency-bound
template<int TS, int IS>
__global__ __launch_bounds__(256) void sta_merge(const float* __restrict__ Opart,
                                                 const float* __restrict__ Ml,
                                                 float* __restrict__ Og) {
    const int bb = blockIdx.x;
    const int b = bb >> 3, slice = bb & 7;
    const int t = threadIdx.x;
    const int row = slice * 16 + (t >> 4);   // 0..127
    const int c4  = t & 15;                  // float4 column
    if (b < NHEADS * NTT) {
        merge_body<TS>(Opart, Ml, Og, b / NTT, IMG_LEN + (b % NTT) * QT,
                       b * TS, row, c4);
    } else {
        const int tile = b - NHEADS * NTT;
        merge_body<IS>(Opart, Ml, Og, tile / NIT, (tile % NIT) * QT,
                       NHEADS * NTT * TS + tile * IS, row, c4);
    }
}

extern "C" void kernel_launch(void* const* d_in, const int* in_sizes, int n_in,
                              void* d_out, int out_size, void* d_ws, size_t ws_size,
                              hipStream_t stream) {
    const float* Qg = (const float*)d_in[0];
    const float* Kg = (const float*)d_in[1];
    const float* Vg = (const float*)d_in[2];
    float* Og = (float*)d_out;
    char* wsb = (char*)d_ws;

    uint4* Kfb = (uint4*)wsb;
    uint4* Vfb = (uint4*)(wsb + KB_BYTES);
    float* Opart = (float*)(wsb + 2 * KB_BYTES);
    const int nprep  = NHEADS * 334 + NHEADS * 2 * 167;   // 1336 + 1336 = 2672
    const int nmerge = NHEADS * (NTT + NIT) * 8;          // 2688

    if (ws_size >= 2 * KB_BYTES + Geo<8, 4>::WS_FLOATS * sizeof(float)) {
        float* Ml = Opart + (size_t)Geo<8, 4>::NPID * QT * DH;
        hipLaunchKernelGGL(sta_prep, dim3(nprep), dim3(256), 0, stream, Kg, Vg, Kfb, Vfb);
        hipLaunchKernelGGL((sta_attn<8, 4, true>), dim3(Geo<8, 4>::NPID * 4), dim3(64), 0, stream,
                           Qg, Kfb, Vfb, Og, Opart, Ml);
        hipLaunchKernelGGL((sta_merge<8, 4>), dim3(nmerge), dim3(256), 0, stream,
                           Opart, Ml, Og);
    } else if (ws_size >= 2 * KB_BYTES + Geo<4, 2>::WS_FLOATS * sizeof(float)) {
        float* Ml = Opart + (size_t)Geo<4, 2>::NPID * QT * DH;
        hipLaunchKernelGGL(sta_prep, dim3(nprep), dim3(256), 0, stream, Kg, Vg, Kfb, Vfb);
        hipLaunchKernelGGL((sta_attn<4, 2, true>), dim3(Geo<4, 2>::NPID * 4), dim3(64), 0, stream,
                           Qg, Kfb, Vfb, Og, Opart, Ml);
        hipLaunchKernelGGL((sta_merge<4, 2>), dim3(nmerge), dim3(256), 0, stream,
                           Opart, Ml, Og);
    } else {
        // last-resort: unsplit, still pre-pass (needs ~22MB; proven ws >= 136MB)
        hipLaunchKernelGGL(sta_prep, dim3(nprep), dim3(256), 0, stream, Kg, Vg, Kfb, Vfb);
        hipLaunchKernelGGL((sta_attn<1, 1, false>), dim3(Geo<1, 1>::NPID * 4), dim3(64), 0, stream,
                           Qg, Kfb, Vfb, Og, (float*)nullptr, (float*)nullptr);
    }
}

// Round 19
// 155.603 us; speedup vs baseline: 1.1375x; 1.1375x over previous
//
#include <hip/hip_runtime.h>

// ---- problem constants (from reference) ----
#define SEQ      10688      // IMG_LEN + TEXT_LEN
#define IMG_LEN  10368      // 18*24*24
#define TEXT_LEN 320
#define DH       128
#define NHEADS   4
#define SLAB     3456       // 6*24*24 tokens per time-slab
#define KVC      32         // kv chunk rows
#define QT       128        // q rows per block (4 waves x 32)
#define NIT      81         // image q-tiles per head
#define NTT      3          // text q-tiles per head (last tile half-valid)
#define NCH_TXT  334
#define NCH_IMG  118        // 108 slab chunks + 10 text chunks
#define SCALEL2E 0.12751744518924593f   // (1/sqrt(128)) * log2(e)
#define DEFER_THR 8.0f      // defer-max rescale threshold (T13)

typedef __bf16 bf16x8 __attribute__((ext_vector_type(8)));
typedef __bf16 bf16x4 __attribute__((ext_vector_type(4)));
typedef float  f32x4  __attribute__((ext_vector_type(4)));

__device__ __forceinline__ unsigned pk2bf(float a, float b) {
    union { __bf16 h[2]; unsigned u; } t;
    t.h[0] = (__bf16)a; t.h[1] = (__bf16)b;
    return t.u;
}

// single-instruction 2^x (we are in log2 domain): exp2f without fast-math
// expands to a ~10-inst guarded sequence; v_exp_f32 IS 2^x on gfx950.
__device__ __forceinline__ float fexp2(float x) {
    float r;
    asm("v_exp_f32 %0, %1" : "=v"(r) : "v"(x));
    return r;
}
// packed f32x2 -> bf16x2 (RNE), one instruction vs ~8 for two scalar casts
__device__ __forceinline__ unsigned cvtpk(float a, float b) {
    unsigned r;
    asm("v_cvt_pk_bf16_f32 %0, %1, %2" : "=v"(r) : "v"(a), "v"(b));
    return r;
}

__device__ __forceinline__ bf16x8 as_bf16x8(uint4 u) {
    union { uint4 a; bf16x8 v; } t; t.a = u; return t.v;
}

__device__ __forceinline__ void split_range(int total, int nsplit, int s, int& c0, int& n) {
    const int q = total / nsplit, r = total % nsplit;
    if (s < r) { c0 = s * (q + 1); n = q + 1; }
    else       { c0 = r * (q + 1) + (s - r) * q; n = q; }
}

template<int TS, int IS> struct Geo {
    static constexpr int NTXTB = NHEADS * NTT * TS;
    static constexpr int NIMGB = NHEADS * NIT * IS;
    static constexpr int NPID  = NTXTB + NIMGB;
    static constexpr size_t WS_FLOATS = (size_t)NPID * (QT * DH + QT * 2);
};
#define KB_BYTES ((size_t)NHEADS * SEQ * DH * 2)   // bf16 K-frag (or V-frag) array

// ---- pre-pass: BOTH K and V to MFMA-fragment order (see R16/R17) ----
__global__ __launch_bounds__(256) void sta_prep(const float* __restrict__ Kg,
                                                const float* __restrict__ Vg,
                                                uint4* __restrict__ Kf,
                                                uint4* __restrict__ Vf) {
    __shared__ float T[64][65];
    const int b = blockIdx.x;
    if (b < NHEADS * 334) {              // K-frag: one block per (head, chunk)
        const int hb = b / 334, chunk = b % 334;
        const float* src = Kg + ((size_t)hb * SEQ + chunk * 32) * DH;
        const int t = threadIdx.x;
        #pragma unroll
        for (int i = 0; i < 2; ++i) {
            const int oidx = t + 256 * i;          // 0..511
            const int frag = oidx >> 6, lane = oidx & 63;
            const int c = frag >> 1, kt = frag & 1;
            const int row = kt * 16 + (lane & 15);
            const int col = c * 32 + (lane >> 4) * 8;
            float4 a = *(const float4*)(src + (size_t)row * DH + col);
            float4 d = *(const float4*)(src + (size_t)row * DH + col + 4);
            uint4 u; u.x = pk2bf(a.x, a.y); u.y = pk2bf(a.z, a.w);
                     u.z = pk2bf(d.x, d.y); u.w = pk2bf(d.z, d.w);
            Kf[((size_t)(hb * 334 + chunk) * 8 + frag) * 64 + lane] = u;
        }
    } else {                             // V: 64kv x 64d tile -> fragment order
        const int bb = b - NHEADS * 334;
        const int dhalf = bb & 1, kvt = (bb >> 1) % 167, h = (bb >> 1) / 167;
        const float* src = Vg + ((size_t)h * SEQ + kvt * 64) * DH + dhalf * 64;
        const int t = threadIdx.x;
        const int col = t & 63, r4 = t >> 6;
        #pragma unroll
        for (int i = 0; i < 16; ++i) {
            const int row = i * 4 + r4;
            T[row][col] = src[(size_t)row * DH + col];
        }
        __syncthreads();
        const int lane = t & 63, q = t & 15, gg = lane >> 4;
        #pragma unroll
        for (int i = 0; i < 2; ++i) {
            const int idx = (t >> 6) * 2 + i;      // 0..7: ch2(2) x kt(2) x dtp(2)
            const int ch2 = idx >> 2, kt = (idx >> 1) & 1, dtp = idx & 1;
            const int kvl = ch2 * 32 + kt * 16 + gg * 4;
            const int dle = dtp * 32 + q;          // d-local of even dt
            const int dlo = dle + 16;
            uint4 u;
            u.x = pk2bf(T[kvl][dle],     T[kvl + 1][dle]);
            u.y = pk2bf(T[kvl + 2][dle], T[kvl + 3][dle]);
            u.z = pk2bf(T[kvl][dlo],     T[kvl + 1][dlo]);
            u.w = pk2bf(T[kvl + 2][dlo], T[kvl + 3][dlo]);
            const size_t o4 = ((size_t)(h * 334 + kvt * 2 + ch2) * 8
                               + kt * 4 + dhalf * 2 + dtp) * 64 + lane;
            Vf[o4] = u;
        }
    }
}

// Barrier-free attn (R17 structure, proven 165us) + single-instruction VALU
// softmax: v_exp_f32 (16/chunk, was ~10-inst exp2f expansion) and
// v_cvt_pk_bf16_f32 for P packing (8/chunk, was ~64 inst of scalar casts).
// VALU was 52% busy and ~630 inst/wave-chunk -- softmax codegen, not math.
// NOTE: NO min-waves clamp (rounds 3/5 spill catastrophe).
template<int TS, int IS, bool SPLIT>
__global__ __launch_bounds__(256) void sta_attn(const float* __restrict__ Qg,
                                                const uint4* __restrict__ Kf,
                                                const uint4* __restrict__ Vf,
                                                float* __restrict__ Og,
                                                float* __restrict__ Opart,
                                                float* __restrict__ Ml) {
    using G = Geo<TS, IS>;
    const int tid  = threadIdx.x;
    const int lane = tid & 63;
    const int wv   = tid >> 6;
    const int q    = lane & 15;       // MFMA col position in S^T (q-tilde)
    const int g    = lane >> 4;       // lane group 0..3

    int b = blockIdx.x;
    int head, qbase, nch, ch0, kvb0, pid = 0;
    bool isText;
    if (b < G::NTXTB) {                        // text splits first (longest poles)
        int tb = b / TS, s = b % TS;
        head = tb / NTT; qbase = IMG_LEN + (tb % NTT) * QT;
        isText = true; kvb0 = 0;
        split_range(NCH_TXT, TS, s, ch0, nch);
        pid = b;
    } else {
        int bb = b - G::NTXTB; int tile = bb / IS, s = bb % IS;
        head = tile / NIT; qbase = (tile % NIT) * QT;
        isText = false; kvb0 = (qbase / SLAB) * SLAB;
        split_range(NCH_IMG, IS, s, ch0, nch);
        pid = G::NTXTB + bb;
    }

    const size_t hoff = (size_t)head * SEQ * DH;
    const float* Qh = Qg + hoff;
    const uint4* kfh = Kf + (size_t)head * 334 * 512 + lane;  // 512 uint4/chunk
    const uint4* vfh = Vf + (size_t)head * 334 * 512 + lane;

    // ---- Q fragments for 2 q-subtiles (B-operand layout), scale folded ----
    bf16x8 qf[2][4];
    #pragma unroll
    for (int n = 0; n < 2; ++n) {
        int qr = qbase + wv * 32 + n * 16 + q;
        if (qr > SEQ - 1) qr = SEQ - 1;        // text tail: clamp (discarded at store)
        const float* qp = Qh + (size_t)qr * DH;
        #pragma unroll
        for (int c = 0; c < 4; ++c) {
            float4 a = *(const float4*)(qp + c * 32 + g * 8);
            float4 d = *(const float4*)(qp + c * 32 + g * 8 + 4);
            union { unsigned u[4]; bf16x8 v; } t;
            t.u[0] = pk2bf(a.x * SCALEL2E, a.y * SCALEL2E);
            t.u[1] = pk2bf(a.z * SCALEL2E, a.w * SCALEL2E);
            t.u[2] = pk2bf(d.x * SCALEL2E, d.y * SCALEL2E);
            t.u[3] = pk2bf(d.z * SCALEL2E, d.w * SCALEL2E);
            qf[n][c] = t.v;
        }
    }

    // o layout (un-swapped PV): o[n][dt][r] = O[q = n*16+g*4+r][d = dt*16+qtilde]
    f32x4 o[2][8];
    #pragma unroll
    for (int n = 0; n < 2; ++n)
        #pragma unroll
        for (int dt = 0; dt < 8; ++dt) o[n][dt] = f32x4{0.f, 0.f, 0.f, 0.f};
    float mrun[2] = {-INFINITY, -INFINITY};    // stats in qtilde-space (lane&15)
    float lsum[2] = {0.f, 0.f};                // per-lane partial (deferred reduce)

    auto kvaddr = [&](int gch) -> int {
        return isText ? gch * KVC
                      : (gch < 108 ? kvb0 + gch * KVC : IMG_LEN + (gch - 108) * KVC);
    };

    // prologue: K fragments for chunk 0
    uint4 kf4[8];
    {
        const uint4* kp = kfh + (size_t)(kvaddr(ch0) >> 5) * 512;
        #pragma unroll
        for (int f = 0; f < 8; ++f) kf4[f] = kp[f * 64];
    }

    for (int ch = 0; ch < nch; ++ch) {
        const int kb = kvaddr(ch0 + ch);

        // ---- V fragments for THIS chunk (oldest in vmcnt queue; consumed at PV) ----
        const uint4* vp = vfh + (size_t)(kb >> 5) * 512;
        uint4 vf4[8];
        #pragma unroll
        for (int f = 0; f < 8; ++f) vf4[f] = vp[f * 64];

        // ---- S^T = K * Q^T from kf4 regs (prefetched last iteration) ----
        f32x4 st[2][2];
        #pragma unroll
        for (int n = 0; n < 2; ++n)
            #pragma unroll
            for (int kt = 0; kt < 2; ++kt) st[n][kt] = f32x4{0.f, 0.f, 0.f, 0.f};
        __builtin_amdgcn_s_setprio(1);
        #pragma unroll
        for (int c = 0; c < 4; ++c) {
            #pragma unroll
            for (int kt = 0; kt < 2; ++kt) {
                bf16x8 kf = as_bf16x8(kf4[c * 2 + kt]);
                st[0][kt] = __builtin_amdgcn_mfma_f32_16x16x32_bf16(kf, qf[0][c], st[0][kt], 0, 0, 0);
                st[1][kt] = __builtin_amdgcn_mfma_f32_16x16x32_bf16(kf, qf[1][c], st[1][kt], 0, 0, 0);
            }
        }
        __builtin_amdgcn_s_setprio(0);

        // ---- online softmax (log2 domain), defer-max; max3-fusable triples ----
        float cm[2];
        #pragma unroll
        for (int n = 0; n < 2; ++n) {
            float a0 = fmaxf(fmaxf(st[n][0][0], st[n][0][1]), st[n][0][2]);
            float a1 = fmaxf(fmaxf(st[n][0][3], st[n][1][0]), st[n][1][1]);
            float a2 = fmaxf(fmaxf(st[n][1][2], st[n][1][3]), a0);
            float c0 = fmaxf(a1, a2);
            c0 = fmaxf(c0, __shfl_xor(c0, 16));
            c0 = fmaxf(c0, __shfl_xor(c0, 32));
            cm[n] = c0;
        }
        if (!__all((cm[0] <= mrun[0] + DEFER_THR) && (cm[1] <= mrun[1] + DEFER_THR))) {
            #pragma unroll
            for (int n = 0; n < 2; ++n) {
                float mnew = fmaxf(mrun[n], cm[n]);
                float sc = fexp2(mrun[n] - mnew);
                lsum[n] *= sc;                 // per-lane partial: same sc, rows match
                mrun[n] = mnew;
                f32x4 scv;
                #pragma unroll
                for (int r = 0; r < 4; ++r)
                    scv[r] = __shfl(sc, (lane & 48) + g * 4 + r);
                #pragma unroll
                for (int dt = 0; dt < 8; ++dt) o[n][dt] *= scv;
            }
        }

        // P in bf16: A-operand layout (m=qtilde, k=g*4+r) IS the st layout.
        bf16x4 pkv[2][2];
        #pragma unroll
        for (int n = 0; n < 2; ++n) {
            float ps = 0.f;
            #pragma unroll
            for (int kt = 0; kt < 2; ++kt) {
                float p0 = fexp2(st[n][kt][0] - mrun[n]);
                float p1 = fexp2(st[n][kt][1] - mrun[n]);
                float p2 = fexp2(st[n][kt][2] - mrun[n]);
                float p3 = fexp2(st[n][kt][3] - mrun[n]);
                ps += (p0 + p1) + (p2 + p3);
                union { unsigned u[2]; bf16x4 v; } t;
                t.u[0] = cvtpk(p0, p1);
                t.u[1] = cvtpk(p2, p3);
                pkv[n][kt] = t.v;
            }
            lsum[n] += ps;
        }

        // ---- prefetch K(ch+1) into the now-dead kf4 regs (flies under PV) ----
        if (ch + 1 < nch) {
            const uint4* kp = kfh + (size_t)(kvaddr(ch0 + ch + 1) >> 5) * 512;
            #pragma unroll
            for (int f = 0; f < 8; ++f) kf4[f] = kp[f * 64];
        }

        // ---- O += P * V : A=pkv regs, B=V frags (registers), no LDS ----
        __builtin_amdgcn_s_setprio(1);
        #pragma unroll
        for (int kt = 0; kt < 2; ++kt) {
            #pragma unroll
            for (int dt = 0; dt < 8; ++dt) {
                bf16x4 vb = ((const bf16x4*)&vf4[kt * 4 + (dt >> 1)])[dt & 1];
                asm("v_mfma_f32_16x16x16_bf16 %0, %1, %2, %0"
                    : "+v"(o[0][dt]) : "v"(pkv[0][kt]), "v"(vb));
                asm("v_mfma_f32_16x16x16_bf16 %0, %1, %2, %0"
                    : "+v"(o[1][dt]) : "v"(pkv[1][kt]), "v"(vb));
            }
        }
        __builtin_amdgcn_s_setprio(0);
    }

    // hazard insurance: asm MFMA writes o[], epilogue VALU reads it soon after
    asm volatile("s_nop 7\n\ts_nop 7");

    // deferred lsum reduction: butterfly across the 4 groups (same qtilde row)
    #pragma unroll
    for (int n = 0; n < 2; ++n) {
        lsum[n] += __shfl_xor(lsum[n], 16);
        lsum[n] += __shfl_xor(lsum[n], 32);
    }

    if constexpr (SPLIT) {
        float* opb = Opart + (size_t)pid * (QT * DH);
        #pragma unroll
        for (int n = 0; n < 2; ++n) {
            #pragma unroll
            for (int r = 0; r < 4; ++r) {
                const int row = wv * 32 + n * 16 + g * 4 + r;
                float* op = opb + row * DH + q;
                #pragma unroll
                for (int dt = 0; dt < 8; ++dt) op[dt * 16] = o[n][dt][r];
            }
            if (g == 0) {
                const int srow = wv * 32 + n * 16 + q;
                Ml[(size_t)pid * (QT * 2) + srow * 2]     = mrun[n];
                Ml[(size_t)pid * (QT * 2) + srow * 2 + 1] = lsum[n];
            }
        }
    } else {
        #pragma unroll
        for (int n = 0; n < 2; ++n) {
            const float inv = 1.f / (lsum[n] + 64.f * fexp2(-mrun[n]));
            f32x4 invv;
            #pragma unroll
            for (int r = 0; r < 4; ++r)
                invv[r] = __shfl(inv, (lane & 48) + g * 4 + r);
            #pragma unroll
            for (int r = 0; r < 4; ++r) {
                const int qrow = qbase + wv * 32 + n * 16 + g * 4 + r;
                if (qrow >= SEQ) continue;
                float* op = Og + hoff + (size_t)qrow * DH + q;
                #pragma unroll
                for (int dt = 0; dt < 8; ++dt) op[dt * 16] = o[n][dt][r] * invv[r];
            }
        }
    }
}

// compile-time-S merge body (runtime-indexed local arrays would go to scratch)
template<int S>
__device__ __forceinline__ void merge_body(const float* __restrict__ Opart,
                                           const float* __restrict__ Ml,
                                           float* __restrict__ Og,
                                           int head, int qbase, int pbase,
                                           int row, int c4) {
    if (qbase + row >= SEQ) return;       // text tail
    float w[S], lv[S];
    float m = -INFINITY;
    #pragma unroll
    for (int s = 0; s < S; ++s) {
        w[s]  = Ml[(size_t)(pbase + s) * (QT * 2) + row * 2];
        lv[s] = Ml[(size_t)(pbase + s) * (QT * 2) + row * 2 + 1];
        m = fmaxf(m, w[s]);
    }
    float L = 64.f * exp2f(-m);           // 64 zero-pad keys (log2 domain)
    #pragma unroll
    for (int s = 0; s < S; ++s) { w[s] = exp2f(w[s] - m); L += w[s] * lv[s]; }
    const float inv = 1.f / L;

    float* op = Og + (size_t)head * SEQ * DH + (size_t)(qbase + row) * DH;
    #pragma unroll
    for (int half = 0; half < 2; ++half) {
        const int j = c4 + half * 16;
        float4 acc = make_float4(0.f, 0.f, 0.f, 0.f);
        #pragma unroll
        for (int s = 0; s < S; ++s) {
            const float4 p = *(const float4*)(Opart + (size_t)(pbase + s) * (QT * DH)
                                              + row * DH + j * 4);
            acc.x += w[s] * p.x; acc.y += w[s] * p.y;
            acc.z += w[s] * p.z; acc.w += w[s] * p.w;
        }
        float4 v; v.x = acc.x * inv; v.y = acc.y * inv; v.z = acc.z * inv; v.w = acc.w * inv;
        *(float4*)(op + j * 4) = v;
    }
}

// 8 blocks per q-tile (16-row slices): 2688 blocks -> not latency-bound
template<int TS, int IS>
__global__ __launch_bounds__(256) void sta_merge(const float* __restrict__ Opart,
                                                 const float* __restrict__ Ml,
                                                 float* __restrict__ Og) {
    const int bb = blockIdx.x;
    const int b = bb >> 3, slice = bb & 7;
    const int t = threadIdx.x;
    const int row = slice * 16 + (t >> 4);   // 0..127
    const int c4  = t & 15;                  // float4 column
    if (b < NHEADS * NTT) {
        merge_body<TS>(Opart, Ml, Og, b / NTT, IMG_LEN + (b % NTT) * QT,
                       b * TS, row, c4);
    } else {
        const int tile = b - NHEADS * NTT;
        merge_body<IS>(Opart, Ml, Og, tile / NIT, (tile % NIT) * QT,
                       NHEADS * NTT * TS + tile * IS, row, c4);
    }
}

extern "C" void kernel_launch(void* const* d_in, const int* in_sizes, int n_in,
                              void* d_out, int out_size, void* d_ws, size_t ws_size,
                              hipStream_t stream) {
    const float* Qg = (const float*)d_in[0];
    const float* Kg = (const float*)d_in[1];
    const float* Vg = (const float*)d_in[2];
    float* Og = (float*)d_out;
    char* wsb = (char*)d_ws;

    uint4* Kfb = (uint4*)wsb;
    uint4* Vfb = (uint4*)(wsb + KB_BYTES);
    float* Opart = (float*)(wsb + 2 * KB_BYTES);
    const int nprep  = NHEADS * 334 + NHEADS * 2 * 167;   // 1336 + 1336 = 2672
    const int nmerge = NHEADS * (NTT + NIT) * 8;          // 2688

    if (ws_size >= 2 * KB_BYTES + Geo<8, 4>::WS_FLOATS * sizeof(float)) {
        float* Ml = Opart + (size_t)Geo<8, 4>::NPID * QT * DH;
        hipLaunchKernelGGL(sta_prep, dim3(nprep), dim3(256), 0, stream, Kg, Vg, Kfb, Vfb);
        hipLaunchKernelGGL((sta_attn<8, 4, true>), dim3(Geo<8, 4>::NPID), dim3(256), 0, stream,
                           Qg, Kfb, Vfb, Og, Opart, Ml);
        hipLaunchKernelGGL((sta_merge<8, 4>), dim3(nmerge), dim3(256), 0, stream,
                           Opart, Ml, Og);
    } else if (ws_size >= 2 * KB_BYTES + Geo<4, 2>::WS_FLOATS * sizeof(float)) {
        float* Ml = Opart + (size_t)Geo<4, 2>::NPID * QT * DH;
        hipLaunchKernelGGL(sta_prep, dim3(nprep), dim3(256), 0, stream, Kg, Vg, Kfb, Vfb);
        hipLaunchKernelGGL((sta_attn<4, 2, true>), dim3(Geo<4, 2>::NPID), dim3(256), 0, stream,
                           Qg, Kfb, Vfb, Og, Opart, Ml);
        hipLaunchKernelGGL((sta_merge<4, 2>), dim3(nmerge), dim3(256), 0, stream,
                           Opart, Ml, Og);
    } else {
        // last-resort: unsplit, still pre-pass (needs ~22MB; proven ws >= 136MB)
        hipLaunchKernelGGL(sta_prep, dim3(nprep), dim3(256), 0, stream, Kg, Vg, Kfb, Vfb);
        hipLaunchKernelGGL((sta_attn<1, 1, false>), dim3(Geo<1, 1>::NPID), dim3(256), 0, stream,
                           Qg, Kfb, Vfb, Og, (float*)nullptr, (float*)nullptr);
    }
}